// Round 1
// baseline (793.372 us; speedup 1.0000x reference)
//
#include <hip/hip_runtime.h>
#include <cstddef>

// Problem constants (B=2, CI=CO=64, NS=16, NPTS=1024)
constexpr int P_TOTAL = 32768;   // B*NS*NPTS
constexpr int NCH     = 64;      // CI == CO
constexpr int PPB     = 32;      // points per block
constexpr int PAD     = 68;     // LDS row stride in floats (272 B, 16B aligned)

// y[o,p] = b[o] + sum_i W[o,i] * x[i*P+p] * (1 + 0.1*eps[p*4096 + o*64 + i])
__global__ void noise_conv_kernel(const float* __restrict__ x,
                                  const float* __restrict__ W,
                                  const float* __restrict__ bias,
                                  const float* __restrict__ eps,
                                  float* __restrict__ out) {
    __shared__ __align__(16) float t_tile[PPB][PAD];  // t_tile[j][i] = x[i*P + p0 + j]

    const int tid  = threadIdx.x;
    const int p0   = blockIdx.x * PPB;
    const int lane = tid & 63;   // output channel o
    const int wave = tid >> 6;   // 0..3

    // Stage x tile into LDS, transposed. Coalesced global reads
    // (consecutive tid -> consecutive p). 2048 floats, 8 per thread.
#pragma unroll
    for (int c = 0; c < (PPB * NCH) / 256; ++c) {
        int e = c * 256 + tid;
        int i = e >> 5;          // e / PPB
        int j = e & (PPB - 1);   // e % PPB
        t_tile[j][i] = x[i * P_TOTAL + p0 + j];
    }

    // Per-lane weight row W[o, :] in registers (64 VGPRs) + bias.
    float4 wrow[16];
    const float4* wp = reinterpret_cast<const float4*>(W + lane * NCH);
#pragma unroll
    for (int k = 0; k < 16; ++k) wrow[k] = wp[k];
    const float bo = bias[lane];

    __syncthreads();

    // Each wave handles PPB/4 = 8 consecutive points.
    for (int r = 0; r < PPB / 4; ++r) {
        const int jr = wave * (PPB / 4) + r;
        const int p  = p0 + jr;
        const float4* ep =
            reinterpret_cast<const float4*>(eps + (size_t)p * (NCH * NCH) + lane * NCH);
        const float4* tp = reinterpret_cast<const float4*>(&t_tile[jr][0]);

        float4 acc = make_float4(0.f, 0.f, 0.f, 0.f);
#pragma unroll
        for (int k = 0; k < 16; ++k) {
            float4 e4 = ep[k];   // eps[p, o, 4k..4k+3]  (16B/lane global load)
            float4 t4 = tp[k];   // broadcast ds_read_b128
            float4 w4 = wrow[k];
            acc.x = fmaf(w4.x * t4.x, fmaf(0.1f, e4.x, 1.f), acc.x);
            acc.y = fmaf(w4.y * t4.y, fmaf(0.1f, e4.y, 1.f), acc.y);
            acc.z = fmaf(w4.z * t4.z, fmaf(0.1f, e4.z, 1.f), acc.z);
            acc.w = fmaf(w4.w * t4.w, fmaf(0.1f, e4.w, 1.f), acc.w);
        }
        out[(size_t)lane * P_TOTAL + p] = (acc.x + acc.y) + (acc.z + acc.w) + bo;
    }
}

extern "C" void kernel_launch(void* const* d_in, const int* in_sizes, int n_in,
                              void* d_out, int out_size, void* d_ws, size_t ws_size,
                              hipStream_t stream) {
    const float* x    = (const float*)d_in[0];  // [2,64,16,1024] -> treated [64, 32768]
    const float* W    = (const float*)d_in[1];  // [64,64]
    const float* bias = (const float*)d_in[2];  // [64]
    const float* eps  = (const float*)d_in[3];  // [32768,64,64]
    float* out        = (float*)d_out;          // [64, 32768] flat

    dim3 grid(P_TOTAL / PPB);  // 1024 blocks
    dim3 block(256);
    noise_conv_kernel<<<grid, block, 0, stream>>>(x, W, bias, eps, out);
}

// Round 2
// 693.361 us; speedup vs baseline: 1.1442x; 1.1442x over previous
//
#include <hip/hip_runtime.h>
#include <cstddef>

// B=2, CI=CO=64, NS=16, NPTS=1024
constexpr int P_TOTAL = 32768;   // total points
constexpr int NCH     = 64;
constexpr int PPB     = 32;      // points per block
constexpr int PPW     = 8;       // points per wave (4 waves/block)
constexpr int XPAD    = 68;      // xt row stride (floats), 16B-aligned, breaks conflicts

// y[o,p] = b[o] + sum_i W[o,i]*x[i,p]*(1 + 0.1*eps[p,o,i])
//
// Coalescing identity: viewing eps[p] (64x64 row-major) as 1024 float4s,
// flat index q = k*64 + lane maps to (o = q>>4, i0 = 4*(q&15)) — and W's flat
// float4 q is exactly W[o][i0..i0+3]. So fully-contiguous 1KB/instr wave
// loads of eps pair element-wise with W4[q] from LDS, no permutation.
__global__ __launch_bounds__(256) void noise_conv_kernel(
    const float* __restrict__ x, const float* __restrict__ W,
    const float* __restrict__ bias, const float* __restrict__ eps,
    float* __restrict__ out)
{
    __shared__ __align__(16) float4 Wl[NCH * NCH / 4];  // 16 KB, flat copy of W
    __shared__ __align__(16) float  xt[PPB][XPAD];      // xt[j][i] = x[i, p0+j]

    const int tid  = threadIdx.x;
    const int lane = tid & 63;
    const int wv   = tid >> 6;        // 0..3
    const int p0   = blockIdx.x * PPB;
    const int g    = lane >> 4;       // 0..3  (o = 4k + g)
    const int s    = lane & 15;       // i-chunk: i0 = 4s

    // Stage W flat (coalesced global, contiguous b128 LDS writes).
    const float4* W4 = reinterpret_cast<const float4*>(W);
#pragma unroll
    for (int c = 0; c < 4; ++c) {
        int idx = c * 256 + tid;
        Wl[idx] = W4[idx];
    }
    // Stage x tile transposed: consecutive tid -> consecutive p (coalesced).
#pragma unroll
    for (int c = 0; c < (PPB * NCH) / 256; ++c) {
        int e = c * 256 + tid;
        int i = e >> 5;               // 0..63
        int j = e & (PPB - 1);        // 0..31
        xt[j][i] = x[i * P_TOTAL + p0 + j];
    }

    const int   o_fin = 4 * s + g;    // channel this lane finally owns
    const float b_fin = bias[o_fin];

    __syncthreads();

    for (int j = 0; j < PPW; ++j) {
        const int jj = wv * PPW + j;
        const int p  = p0 + jj;
        const float4* ep4 = reinterpret_cast<const float4*>(eps)
                          + (size_t)p * (NCH * NCH / 4) + lane;

        // 16 fully-coalesced 1KB wave loads: the whole 16KB eps row of point p.
        float4 e[16];
#pragma unroll
        for (int k = 0; k < 16; ++k) e[k] = ep4[k * 64];

        const float4 x4 = *reinterpret_cast<const float4*>(&xt[jj][4 * s]);

        // acc[k] = sum over this lane's 4 i's of W*x*(1+0.1*eps), for o=4k+g
        float acc[16];
#pragma unroll
        for (int k = 0; k < 16; ++k) {
            float4 w4 = Wl[k * 64 + lane];   // contiguous b128, conflict-free
            float wx0 = w4.x * x4.x, wx1 = w4.y * x4.y;
            float wx2 = w4.z * x4.z, wx3 = w4.w * x4.w;
            float f0 = fmaf(0.1f, e[k].x, 1.0f);
            float f1 = fmaf(0.1f, e[k].y, 1.0f);
            float f2 = fmaf(0.1f, e[k].z, 1.0f);
            float f3 = fmaf(0.1f, e[k].w, 1.0f);
            float a  = wx0 * f0;
            a = fmaf(wx1, f1, a);
            a = fmaf(wx2, f2, a);
            a = fmaf(wx3, f3, a);
            acc[k] = a;
        }

        // Reduce-scatter over the 16 i-chunk lanes (lane bits 0..3):
        // 15 shuffles; lane l ends holding the full sum for o = 4*(l&15)+(l>>4).
        float r8[8];
#pragma unroll
        for (int t = 0; t < 8; ++t) {
            float mine  = (s & 8) ? acc[t + 8] : acc[t];
            float other = (s & 8) ? acc[t]     : acc[t + 8];
            r8[t] = mine + __shfl_xor(other, 8, 64);
        }
        float r4[4];
#pragma unroll
        for (int t = 0; t < 4; ++t) {
            float mine  = (s & 4) ? r8[t + 4] : r8[t];
            float other = (s & 4) ? r8[t]     : r8[t + 4];
            r4[t] = mine + __shfl_xor(other, 4, 64);
        }
        float r2[2];
#pragma unroll
        for (int t = 0; t < 2; ++t) {
            float mine  = (s & 2) ? r4[t + 2] : r4[t];
            float other = (s & 2) ? r4[t]     : r4[t + 2];
            r2[t] = mine + __shfl_xor(other, 2, 64);
        }
        {
            float mine  = (s & 1) ? r2[1] : r2[0];
            float other = (s & 1) ? r2[0] : r2[1];
            float y = mine + __shfl_xor(other, 1, 64) + b_fin;
            out[(size_t)o_fin * P_TOTAL + p] = y;
        }
    }
}

extern "C" void kernel_launch(void* const* d_in, const int* in_sizes, int n_in,
                              void* d_out, int out_size, void* d_ws, size_t ws_size,
                              hipStream_t stream) {
    const float* x    = (const float*)d_in[0];  // [64, 32768] after reshape
    const float* W    = (const float*)d_in[1];  // [64,64]
    const float* bias = (const float*)d_in[2];  // [64]
    const float* eps  = (const float*)d_in[3];  // [32768,64,64]
    float* out        = (float*)d_out;          // [64, 32768]

    dim3 grid(P_TOTAL / PPB);   // 1024 blocks
    dim3 block(256);
    noise_conv_kernel<<<grid, block, 0, stream>>>(x, W, bias, eps, out);
}